// Round 1
// baseline (2174.132 us; speedup 1.0000x reference)
//
#include <hip/hip_runtime.h>
#include <math.h>

#define G 8
#define N0 16384
#define NEDGE (G*N0*8)      // 1048576
#define C 128
#define HID 256
#define OUTF 128
#define EPS_FA 0.1f
#define SMAX 2048

// ---------------- init ----------------
__global__ void k_init_edges(const int* __restrict__ ei, int* __restrict__ srcA,
                             int* __restrict__ dstA, unsigned char* __restrict__ em) {
    int e = blockIdx.x * 256 + threadIdx.x;
    if (e < NEDGE) { srcA[e] = ei[e]; dstA[e] = ei[NEDGE + e]; em[e] = 1; }
}

__global__ void k_zero_pooled(float* p) {
    int i = blockIdx.x * 256 + threadIdx.x;
    if (i < G * 384) p[i] = 0.0f;
}

// ---------------- per-node attention dots + zero scratch ----------------
// one wave (64 lanes) per node; lane handles 2 channels
__global__ void k_alar(const float* __restrict__ cur,
                       const float* __restrict__ attl, const float* __restrict__ attr,
                       float* __restrict__ al, float* __restrict__ ar,
                       int* __restrict__ degI, int* __restrict__ score,
                       unsigned char* __restrict__ keep, int* __restrict__ nmap, int n) {
    int wid  = (blockIdx.x * blockDim.x + threadIdx.x) >> 6;
    int lane = threadIdx.x & 63;
    if (wid >= n) return;
    float2 v  = ((const float2*)(cur + (size_t)wid * C))[lane];
    float2 l2 = ((const float2*)attl)[lane];
    float2 r2 = ((const float2*)attr)[lane];
    float sl = v.x * l2.x + v.y * l2.y;
    float sr = v.x * r2.x + v.y * r2.y;
    for (int o = 32; o >= 1; o >>= 1) { sl += __shfl_xor(sl, o); sr += __shfl_xor(sr, o); }
    if (lane == 0) {
        al[wid] = sl; ar[wid] = sr;
        degI[wid] = 0; score[wid] = 0; keep[wid] = 0; nmap[wid] = 0;
    }
}

// ---------------- degree / score accumulation ----------------
__global__ void k_degscore(const int* __restrict__ src, const int* __restrict__ dst,
                           const unsigned char* __restrict__ em,
                           int* __restrict__ degI, int* __restrict__ score) {
    int e = blockIdx.x * 256 + threadIdx.x;
    if (e >= NEDGE) return;
    if (em[e]) { atomicAdd(&degI[dst[e]], 1); atomicAdd(&score[src[e]], 1); }
}

// ---------------- dinv + self-loop coefficient ----------------
__global__ void k_selfco(const int* __restrict__ degI, const float* __restrict__ al,
                         const float* __restrict__ ar, float* __restrict__ dinv,
                         float* __restrict__ selfco, int n) {
    int v = blockIdx.x * 256 + threadIdx.x;
    if (v >= n) return;
    float d  = (float)degI[v] + 1.0f;
    float di = rsqrtf(d);
    dinv[v]   = di;
    selfco[v] = di * di * tanhf(al[v] + ar[v]);
}

// ---------------- h init: self-loop + eps*x0 ----------------
__global__ void k_hinit(const float* __restrict__ cur, const float* __restrict__ x,
                        const int* __restrict__ oidx, const float* __restrict__ selfco,
                        float* __restrict__ h, int n) {
    int i = blockIdx.x * 256 + threadIdx.x;
    if (i >= n * 32) return;
    int v = i >> 5, c4 = i & 31;
    int o = oidx ? oidx[v] : v;
    float4 cv = ((const float4*)(cur + (size_t)v * C))[c4];
    float4 xv = ((const float4*)(x   + (size_t)o * C))[c4];
    float s = selfco[v];
    float4 r;
    r.x = s * cv.x + EPS_FA * xv.x;
    r.y = s * cv.y + EPS_FA * xv.y;
    r.z = s * cv.z + EPS_FA * xv.z;
    r.w = s * cv.w + EPS_FA * xv.w;
    ((float4*)(h + (size_t)v * C))[c4] = r;
}

// ---------------- per-edge coefficient ----------------
__global__ void k_coef(const int* __restrict__ src, const int* __restrict__ dst,
                       const unsigned char* __restrict__ em, const float* __restrict__ dinv,
                       const float* __restrict__ al, const float* __restrict__ ar,
                       float* __restrict__ coef) {
    int e = blockIdx.x * 256 + threadIdx.x;
    if (e >= NEDGE) return;
    float c = 0.0f;
    if (em[e]) {
        int s = src[e], d = dst[e];
        c = dinv[s] * dinv[d] * tanhf(al[d] + ar[s]);
    }
    coef[e] = c;
}

// ---------------- edge messages: one wave per edge ----------------
__global__ void k_msg(const int* __restrict__ src, const int* __restrict__ dst,
                      const float* __restrict__ coef, const float* __restrict__ cur,
                      float* __restrict__ h) {
    int e = (blockIdx.x << 2) + (threadIdx.x >> 6);
    int lane = threadIdx.x & 63;
    if (e >= NEDGE) return;
    float cf = coef[e];
    if (cf == 0.0f) return;
    int s = src[e], d = dst[e];
    float2 v = ((const float2*)(cur + (size_t)s * C))[lane];
    float* hp = h + (size_t)d * C + lane * 2;
    atomicAdd(hp,     cf * v.x);
    atomicAdd(hp + 1, cf * v.y);
}

// ---------------- per-graph max pool (relu folded) ----------------
__global__ void k_pool(const float* __restrict__ h, float* __restrict__ pooled,
                       int npg, int layer) {
    int g = blockIdx.x, chunk = blockIdx.y, c = threadIdx.x;
    int r0 = chunk * 256;
    float m = 0.0f; // relu floor
    const float* base = h + ((size_t)g * npg + r0) * C + c;
    for (int r = 0; r < 256; r++) m = fmaxf(m, base[(size_t)r * C]);
    atomicMax((unsigned int*)&pooled[g * 384 + layer * 128 + c], __float_as_uint(m));
}

// ---------------- exact stable top-k per graph ----------------
__global__ void __launch_bounds__(256) k_topk(const int* __restrict__ score, int npg, int k,
                                              unsigned char* __restrict__ keep,
                                              int* __restrict__ nmap, int* __restrict__ perm) {
    int g = blockIdx.x, tid = threadIdx.x;
    __shared__ int hist[SMAX];
    __shared__ int basepos[SMAX];
    __shared__ int run[SMAX];
    __shared__ int cs[256];
    for (int s = tid; s < SMAX; s += 256) { hist[s] = 0; run[s] = 0; }
    __syncthreads();
    const int* sc = score + g * npg;
    for (int v = tid; v < npg; v += 256) {
        int s = sc[v]; if (s > SMAX - 1) s = SMAX - 1;
        atomicAdd(&hist[s], 1);
    }
    __syncthreads();
    if (tid == 0) {
        int acc = 0;
        for (int s = SMAX - 1; s >= 0; s--) { basepos[s] = acc; acc += hist[s]; }
    }
    __syncthreads();
    for (int v0 = 0; v0 < npg; v0 += 256) {
        int v = v0 + tid;
        int s = sc[v]; if (s > SMAX - 1) s = SMAX - 1;
        cs[tid] = s;
        __syncthreads();
        int cnt = 0;
        for (int u = 0; u < tid; u++) cnt += (cs[u] == s);
        int pos = basepos[s] + run[s] + cnt;
        if (pos < k) {
            int vg = g * npg + v;
            int nid = g * k + pos;
            keep[vg] = 1; nmap[vg] = nid; perm[nid] = vg;
        }
        __syncthreads();
        atomicAdd(&run[s], 1);
        __syncthreads();
    }
}

// ---------------- gather kept nodes (relu folded) + oidx chain ----------------
__global__ void k_gather(const float* __restrict__ h, const int* __restrict__ perm,
                         const int* __restrict__ oidx, float* __restrict__ curN,
                         int* __restrict__ oidxN, int m) {
    int i = blockIdx.x * 256 + threadIdx.x;
    if (i >= m * 32) return;
    int j = i >> 5, c4 = i & 31;
    int p = perm[j];
    float4 v = ((const float4*)(h + (size_t)p * C))[c4];
    v.x = fmaxf(v.x, 0.0f); v.y = fmaxf(v.y, 0.0f);
    v.z = fmaxf(v.z, 0.0f); v.w = fmaxf(v.w, 0.0f);
    ((float4*)(curN + (size_t)j * C))[c4] = v;
    if (c4 == 0) oidxN[j] = oidx ? oidx[p] : p;
}

// ---------------- remap edges in place ----------------
__global__ void k_remap(int* __restrict__ src, int* __restrict__ dst,
                        unsigned char* __restrict__ em,
                        const unsigned char* __restrict__ keep, const int* __restrict__ nmap) {
    int e = blockIdx.x * 256 + threadIdx.x;
    if (e >= NEDGE) return;
    int s = src[e], d = dst[e];
    if (em[e] && keep[s] && keep[d]) { src[e] = nmap[s]; dst[e] = nmap[d]; }
    else { em[e] = 0; src[e] = 0; dst[e] = 0; }
}

// ---------------- GRU + final linears ----------------
__global__ void __launch_bounds__(256) k_tail(const float* __restrict__ pooled,
        const float* __restrict__ wih, const float* __restrict__ bih,
        const float* __restrict__ bhh, const float* __restrict__ wfin,
        const float* __restrict__ bfin, const float* __restrict__ wroot,
        const float* __restrict__ broot, const float* __restrict__ rootv,
        const float* __restrict__ alphap, float* __restrict__ out) {
    int g = blockIdx.x, t = threadIdx.x;
    __shared__ float fused[384];
    __shared__ float gi[768];
    __shared__ float hg[256];
    for (int j = t; j < 384; j += 256) fused[j] = pooled[g * 384 + j];
    __syncthreads();
    for (int r = t; r < 768; r += 256) {
        float s = bih[r];
        const float* w = wih + (size_t)r * 384;
        for (int j = 0; j < 384; j++) s += w[j] * fused[j];
        gi[r] = s;
    }
    __syncthreads();
    if (t < 256) {
        float r  = 1.0f / (1.0f + expf(-(gi[t]       + bhh[t])));
        float z  = 1.0f / (1.0f + expf(-(gi[256 + t] + bhh[256 + t])));
        float nc = tanhf(gi[512 + t] + r * bhh[512 + t]);
        hg[t] = (1.0f - z) * nc;
    }
    __syncthreads();
    if (t < 128) {
        float o = bfin[t];
        const float* w = wfin + (size_t)t * 256;
        for (int j = 0; j < 256; j++) o += w[j] * hg[j];
        float re = broot[t];
        const float* wr = wroot + (size_t)t * 128;
        const float* rg = rootv + (size_t)g * 128;
        for (int j = 0; j < 128; j++) re += wr[j] * rg[j];
        float a = alphap[0];
        out[g * 128 + t] = a * o + (1.0f - a) * re;
    }
}

extern "C" void kernel_launch(void* const* d_in, const int* in_sizes, int n_in,
                              void* d_out, int out_size, void* d_ws, size_t ws_size,
                              hipStream_t stream) {
    const float* x      = (const float*)d_in[0];
    const int*   ei     = (const int*)d_in[1];
    const float* rootv  = (const float*)d_in[3];
    const float* att_l  = (const float*)d_in[4];
    const float* att_r  = (const float*)d_in[5];
    const float* w_ih   = (const float*)d_in[6];
    const float* b_ih   = (const float*)d_in[8];
    const float* b_hh   = (const float*)d_in[9];
    const float* w_fin  = (const float*)d_in[10];
    const float* b_fin  = (const float*)d_in[11];
    const float* w_root = (const float*)d_in[12];
    const float* b_root = (const float*)d_in[13];
    const float* alphap = (const float*)d_in[14];
    float* out = (float*)d_out;

    char* wsb = (char*)d_ws;
    size_t off = 0;
    auto alloc = [&](size_t bytes) -> char* {
        char* p = wsb + off; off += (bytes + 255) & ~(size_t)255; return p;
    };
    float* bufH   = (float*)alloc((size_t)131072 * C * 4);
    float* bufC   = (float*)alloc((size_t)65536  * C * 4);
    int*   srcA   = (int*)alloc((size_t)NEDGE * 4);
    int*   dstA   = (int*)alloc((size_t)NEDGE * 4);
    unsigned char* emask = (unsigned char*)alloc(NEDGE);
    float* coef   = (float*)alloc((size_t)NEDGE * 4);
    float* al     = (float*)alloc(131072 * 4);
    float* ar     = (float*)alloc(131072 * 4);
    float* dinv   = (float*)alloc(131072 * 4);
    float* selfco = (float*)alloc(131072 * 4);
    int*   degI   = (int*)alloc(131072 * 4);
    int*   score  = (int*)alloc(131072 * 4);
    unsigned char* keep = (unsigned char*)alloc(131072);
    int*   nmap   = (int*)alloc(131072 * 4);
    int*   perm   = (int*)alloc(65536 * 4);
    int*   oidxA  = (int*)alloc(65536 * 4);
    int*   oidxB  = (int*)alloc(32768 * 4);
    float* pooled = (float*)alloc(G * 384 * 4);

    k_init_edges<<<(NEDGE + 255) / 256, 256, 0, stream>>>(ei, srcA, dstA, emask);
    k_zero_pooled<<<(G * 384 + 255) / 256, 256, 0, stream>>>(pooled);

    const int ns[3]   = {131072, 65536, 32768};
    const int npgs[3] = {16384, 8192, 4096};
    const int ks[3]   = {8192, 4096, 0};

    for (int l = 0; l < 3; l++) {
        int n = ns[l], npg = npgs[l], k = ks[l];
        const float* cur  = (l == 0) ? x : bufC;
        const int*   oidx = (l == 0) ? nullptr : (l == 1 ? oidxA : oidxB);
        int* oidxN        = (l == 0) ? oidxA : oidxB;

        k_alar<<<n / 4, 256, 0, stream>>>(cur, att_l + l * C, att_r + l * C,
                                          al, ar, degI, score, keep, nmap, n);
        k_degscore<<<(NEDGE + 255) / 256, 256, 0, stream>>>(srcA, dstA, emask, degI, score);
        k_selfco<<<(n + 255) / 256, 256, 0, stream>>>(degI, al, ar, dinv, selfco, n);
        k_hinit<<<(n * 32 + 255) / 256, 256, 0, stream>>>(cur, x, oidx, selfco, bufH, n);
        k_coef<<<(NEDGE + 255) / 256, 256, 0, stream>>>(srcA, dstA, emask, dinv, al, ar, coef);
        k_msg<<<NEDGE / 4, 256, 0, stream>>>(srcA, dstA, coef, cur, bufH);
        k_pool<<<dim3(G, npg / 256), 128, 0, stream>>>(bufH, pooled, npg, l);

        if (l < 2) {
            k_topk<<<G, 256, 0, stream>>>(score, npg, k, keep, nmap, perm);
            int m = G * k;
            k_gather<<<(m * 32 + 255) / 256, 256, 0, stream>>>(bufH, perm, oidx, bufC, oidxN, m);
            k_remap<<<(NEDGE + 255) / 256, 256, 0, stream>>>(srcA, dstA, emask, keep, nmap);
        }
    }

    k_tail<<<G, 256, 0, stream>>>(pooled, w_ih, b_ih, b_hh, w_fin, b_fin,
                                  w_root, b_root, rootv, alphap, out);
}

// Round 2
// 1154.484 us; speedup vs baseline: 1.8832x; 1.8832x over previous
//
#include <hip/hip_runtime.h>
#include <math.h>

#define G 8
#define N0 16384
#define NEDGE (G*N0*8)      // 1048576
#define C 128
#define EPS_FA 0.1f
#define SMAX 2048

// ---------------- init ----------------
__global__ void k_init_edges(const int* __restrict__ ei, int* __restrict__ srcA,
                             int* __restrict__ dstA, unsigned char* __restrict__ em) {
    int e = blockIdx.x * 256 + threadIdx.x;
    if (e < NEDGE) { srcA[e] = ei[e]; dstA[e] = ei[NEDGE + e]; em[e] = 1; }
}

__global__ void k_zero_pooled(float* p) {
    int i = blockIdx.x * 256 + threadIdx.x;
    if (i < G * 384) p[i] = 0.0f;
}

// ---------------- per-node attention dots + zero scratch ----------------
__global__ void k_alar(const float* __restrict__ cur,
                       const float* __restrict__ attl, const float* __restrict__ attr,
                       float* __restrict__ al, float* __restrict__ ar,
                       int* __restrict__ degI, int* __restrict__ score,
                       unsigned char* __restrict__ keep, int* __restrict__ nmap, int n) {
    int wid  = (blockIdx.x * blockDim.x + threadIdx.x) >> 6;
    int lane = threadIdx.x & 63;
    if (wid >= n) return;
    float2 v  = ((const float2*)(cur + (size_t)wid * C))[lane];
    float2 l2 = ((const float2*)attl)[lane];
    float2 r2 = ((const float2*)attr)[lane];
    float sl = v.x * l2.x + v.y * l2.y;
    float sr = v.x * r2.x + v.y * r2.y;
    for (int o = 32; o >= 1; o >>= 1) { sl += __shfl_xor(sl, o); sr += __shfl_xor(sr, o); }
    if (lane == 0) {
        al[wid] = sl; ar[wid] = sr;
        degI[wid] = 0; score[wid] = 0; keep[wid] = 0; nmap[wid] = 0;
    }
}

// ---------------- degree / score accumulation ----------------
__global__ void k_degscore(const int* __restrict__ src, const int* __restrict__ dst,
                           const unsigned char* __restrict__ em,
                           int* __restrict__ degI, int* __restrict__ score) {
    int e = blockIdx.x * 256 + threadIdx.x;
    if (e >= NEDGE) return;
    if (em[e]) { atomicAdd(&degI[dst[e]], 1); atomicAdd(&score[src[e]], 1); }
}

// ---------------- dinv + self-loop coefficient ----------------
__global__ void k_selfco(const int* __restrict__ degI, const float* __restrict__ al,
                         const float* __restrict__ ar, float* __restrict__ dinv,
                         float* __restrict__ selfco, int n) {
    int v = blockIdx.x * 256 + threadIdx.x;
    if (v >= n) return;
    float d  = (float)degI[v] + 1.0f;
    float di = rsqrtf(d);
    dinv[v]   = di;
    selfco[v] = di * di * tanhf(al[v] + ar[v]);
}

// ---------------- prefix scan: degI -> rowptr (exclusive), cursor copy ----------------
// scan1: 2048 elements per block (256 thr x 8)
__global__ void __launch_bounds__(256) k_scan1(const int* __restrict__ degI,
                                               int* __restrict__ rowptr,
                                               int* __restrict__ bsum) {
    __shared__ int part[256];
    int t = threadIdx.x;
    int base = blockIdx.x * 2048 + t * 8;
    int v[8]; int s = 0;
    for (int i = 0; i < 8; i++) { v[i] = degI[base + i]; s += v[i]; }
    part[t] = s; __syncthreads();
    for (int o = 1; o < 256; o <<= 1) {
        int val = part[t];
        int add = (t >= o) ? part[t - o] : 0;
        __syncthreads();
        part[t] = val + add;
        __syncthreads();
    }
    int run = (t == 0) ? 0 : part[t - 1];
    if (t == 255) bsum[blockIdx.x] = part[255];
    for (int i = 0; i < 8; i++) { rowptr[base + i] = run; run += v[i]; }
}

__global__ void k_scan2(int* __restrict__ bsum, int nb) {
    if (threadIdx.x == 0 && blockIdx.x == 0) {
        int acc = 0;
        for (int i = 0; i < nb; i++) { int v = bsum[i]; bsum[i] = acc; acc += v; }
    }
}

__global__ void k_scan3(int* __restrict__ rowptr, int* __restrict__ cursor,
                        const int* __restrict__ bsum, int n) {
    int i = blockIdx.x * 256 + threadIdx.x;
    if (i >= n) return;
    int v = rowptr[i] + bsum[i >> 11];
    rowptr[i] = v; cursor[i] = v;
}

// ---------------- fill CSR (coef computed inline) ----------------
__global__ void k_fill(const int* __restrict__ src, const int* __restrict__ dst,
                       const unsigned char* __restrict__ em,
                       const float* __restrict__ dinv, const float* __restrict__ al,
                       const float* __restrict__ ar,
                       int* __restrict__ cursor, int* __restrict__ srcE,
                       float* __restrict__ cfE) {
    int e = blockIdx.x * 256 + threadIdx.x;
    if (e >= NEDGE) return;
    if (!em[e]) return;
    int s = src[e], d = dst[e];
    float cf = dinv[s] * dinv[d] * tanhf(al[d] + ar[s]);
    int pos = atomicAdd(&cursor[d], 1);
    srcE[pos] = s; cfE[pos] = cf;
}

// ---------------- CSR gather messages: one wave per dst node ----------------
// h[v] = relu( sum_e cf*cur[src] + selfco[v]*cur[v] + EPS*x[oidx[v]] )
__global__ void k_msg_csr(const int* __restrict__ rowptr, const int* __restrict__ degI,
                          const int* __restrict__ srcE, const float* __restrict__ cfE,
                          const float* __restrict__ cur, const float* __restrict__ x,
                          const int* __restrict__ oidx, const float* __restrict__ selfco,
                          float* __restrict__ h, int n) {
    int wid  = (blockIdx.x * blockDim.x + threadIdx.x) >> 6;
    int lane = threadIdx.x & 63;
    if (wid >= n) return;
    int rs = rowptr[wid], deg = degI[wid];
    float accx = 0.0f, accy = 0.0f;
    for (int j = rs; j < rs + deg; j++) {
        int s = srcE[j];
        float cf = cfE[j];
        float2 v = ((const float2*)(cur + (size_t)s * C))[lane];
        accx += cf * v.x; accy += cf * v.y;
    }
    int o = oidx ? oidx[wid] : wid;
    float2 cv = ((const float2*)(cur + (size_t)wid * C))[lane];
    float2 xv = ((const float2*)(x   + (size_t)o   * C))[lane];
    float sc = selfco[wid];
    float2 r;
    r.x = fmaxf(accx + sc * cv.x + EPS_FA * xv.x, 0.0f);
    r.y = fmaxf(accy + sc * cv.y + EPS_FA * xv.y, 0.0f);
    ((float2*)(h + (size_t)wid * C))[lane] = r;
}

// ---------------- per-graph max pool (h already relu'd) ----------------
__global__ void k_pool(const float* __restrict__ h, float* __restrict__ pooled,
                       int npg, int layer) {
    int g = blockIdx.x, chunk = blockIdx.y, c = threadIdx.x;
    int r0 = chunk * 256;
    float m = 0.0f;
    const float* base = h + ((size_t)g * npg + r0) * C + c;
    for (int r = 0; r < 256; r++) m = fmaxf(m, base[(size_t)r * C]);
    atomicMax((unsigned int*)&pooled[g * 384 + layer * 128 + c], __float_as_uint(m));
}

// ---------------- exact stable top-k per graph ----------------
__global__ void __launch_bounds__(256) k_topk(const int* __restrict__ score, int npg, int k,
                                              unsigned char* __restrict__ keep,
                                              int* __restrict__ nmap, int* __restrict__ perm) {
    int g = blockIdx.x, tid = threadIdx.x;
    __shared__ int hist[SMAX];
    __shared__ int basepos[SMAX];
    __shared__ int run[SMAX];
    __shared__ int cs[256];
    for (int s = tid; s < SMAX; s += 256) { hist[s] = 0; run[s] = 0; }
    __syncthreads();
    const int* sc = score + g * npg;
    for (int v = tid; v < npg; v += 256) {
        int s = sc[v]; if (s > SMAX - 1) s = SMAX - 1;
        atomicAdd(&hist[s], 1);
    }
    __syncthreads();
    if (tid == 0) {
        int acc = 0;
        for (int s = SMAX - 1; s >= 0; s--) { basepos[s] = acc; acc += hist[s]; }
    }
    __syncthreads();
    for (int v0 = 0; v0 < npg; v0 += 256) {
        int v = v0 + tid;
        int s = sc[v]; if (s > SMAX - 1) s = SMAX - 1;
        cs[tid] = s;
        __syncthreads();
        int cnt = 0;
        for (int u = 0; u < tid; u++) cnt += (cs[u] == s);
        int pos = basepos[s] + run[s] + cnt;
        if (pos < k) {
            int vg = g * npg + v;
            int nid = g * k + pos;
            keep[vg] = 1; nmap[vg] = nid; perm[nid] = vg;
        }
        __syncthreads();
        atomicAdd(&run[s], 1);
        __syncthreads();
    }
}

// ---------------- gather kept nodes + oidx chain ----------------
__global__ void k_gather(const float* __restrict__ h, const int* __restrict__ perm,
                         const int* __restrict__ oidx, float* __restrict__ curN,
                         int* __restrict__ oidxN, int m) {
    int i = blockIdx.x * 256 + threadIdx.x;
    if (i >= m * 32) return;
    int j = i >> 5, c4 = i & 31;
    int p = perm[j];
    float4 v = ((const float4*)(h + (size_t)p * C))[c4];
    ((float4*)(curN + (size_t)j * C))[c4] = v;
    if (c4 == 0) oidxN[j] = oidx ? oidx[p] : p;
}

// ---------------- remap edges in place ----------------
__global__ void k_remap(int* __restrict__ src, int* __restrict__ dst,
                        unsigned char* __restrict__ em,
                        const unsigned char* __restrict__ keep, const int* __restrict__ nmap) {
    int e = blockIdx.x * 256 + threadIdx.x;
    if (e >= NEDGE) return;
    int s = src[e], d = dst[e];
    if (em[e] && keep[s] && keep[d]) { src[e] = nmap[s]; dst[e] = nmap[d]; }
    else { em[e] = 0; src[e] = 0; dst[e] = 0; }
}

// ---------------- GRU + final linears ----------------
__global__ void __launch_bounds__(256) k_tail(const float* __restrict__ pooled,
        const float* __restrict__ wih, const float* __restrict__ bih,
        const float* __restrict__ bhh, const float* __restrict__ wfin,
        const float* __restrict__ bfin, const float* __restrict__ wroot,
        const float* __restrict__ broot, const float* __restrict__ rootv,
        const float* __restrict__ alphap, float* __restrict__ out) {
    int g = blockIdx.x, t = threadIdx.x;
    __shared__ float fused[384];
    __shared__ float gi[768];
    __shared__ float hg[256];
    for (int j = t; j < 384; j += 256) fused[j] = pooled[g * 384 + j];
    __syncthreads();
    for (int r = t; r < 768; r += 256) {
        float s = bih[r];
        const float* w = wih + (size_t)r * 384;
        for (int j = 0; j < 384; j++) s += w[j] * fused[j];
        gi[r] = s;
    }
    __syncthreads();
    if (t < 256) {
        float r  = 1.0f / (1.0f + expf(-(gi[t]       + bhh[t])));
        float z  = 1.0f / (1.0f + expf(-(gi[256 + t] + bhh[256 + t])));
        float nc = tanhf(gi[512 + t] + r * bhh[512 + t]);
        hg[t] = (1.0f - z) * nc;
    }
    __syncthreads();
    if (t < 128) {
        float o = bfin[t];
        const float* w = wfin + (size_t)t * 256;
        for (int j = 0; j < 256; j++) o += w[j] * hg[j];
        float re = broot[t];
        const float* wr = wroot + (size_t)t * 128;
        const float* rg = rootv + (size_t)g * 128;
        for (int j = 0; j < 128; j++) re += wr[j] * rg[j];
        float a = alphap[0];
        out[g * 128 + t] = a * o + (1.0f - a) * re;
    }
}

extern "C" void kernel_launch(void* const* d_in, const int* in_sizes, int n_in,
                              void* d_out, int out_size, void* d_ws, size_t ws_size,
                              hipStream_t stream) {
    const float* x      = (const float*)d_in[0];
    const int*   ei     = (const int*)d_in[1];
    const float* rootv  = (const float*)d_in[3];
    const float* att_l  = (const float*)d_in[4];
    const float* att_r  = (const float*)d_in[5];
    const float* w_ih   = (const float*)d_in[6];
    const float* b_ih   = (const float*)d_in[8];
    const float* b_hh   = (const float*)d_in[9];
    const float* w_fin  = (const float*)d_in[10];
    const float* b_fin  = (const float*)d_in[11];
    const float* w_root = (const float*)d_in[12];
    const float* b_root = (const float*)d_in[13];
    const float* alphap = (const float*)d_in[14];
    float* out = (float*)d_out;

    char* wsb = (char*)d_ws;
    size_t off = 0;
    auto alloc = [&](size_t bytes) -> char* {
        char* p = wsb + off; off += (bytes + 255) & ~(size_t)255; return p;
    };
    float* bufH   = (float*)alloc((size_t)131072 * C * 4);
    float* bufC   = (float*)alloc((size_t)65536  * C * 4);
    int*   srcA   = (int*)alloc((size_t)NEDGE * 4);
    int*   dstA   = (int*)alloc((size_t)NEDGE * 4);
    unsigned char* emask = (unsigned char*)alloc(NEDGE);
    int*   srcE   = (int*)alloc((size_t)NEDGE * 4);
    float* cfE    = (float*)alloc((size_t)NEDGE * 4);
    float* al     = (float*)alloc(131072 * 4);
    float* ar     = (float*)alloc(131072 * 4);
    float* dinv   = (float*)alloc(131072 * 4);
    float* selfco = (float*)alloc(131072 * 4);
    int*   degI   = (int*)alloc(131072 * 4);
    int*   score  = (int*)alloc(131072 * 4);
    int*   rowptr = (int*)alloc(131072 * 4);
    int*   cursor = (int*)alloc(131072 * 4);
    int*   bsum   = (int*)alloc(256 * 4);
    unsigned char* keep = (unsigned char*)alloc(131072);
    int*   nmap   = (int*)alloc(131072 * 4);
    int*   perm   = (int*)alloc(65536 * 4);
    int*   oidxA  = (int*)alloc(65536 * 4);
    int*   oidxB  = (int*)alloc(32768 * 4);
    float* pooled = (float*)alloc(G * 384 * 4);

    k_init_edges<<<(NEDGE + 255) / 256, 256, 0, stream>>>(ei, srcA, dstA, emask);
    k_zero_pooled<<<(G * 384 + 255) / 256, 256, 0, stream>>>(pooled);

    const int ns[3]   = {131072, 65536, 32768};
    const int npgs[3] = {16384, 8192, 4096};
    const int ks[3]   = {8192, 4096, 0};

    for (int l = 0; l < 3; l++) {
        int n = ns[l], npg = npgs[l], k = ks[l];
        const float* cur  = (l == 0) ? x : bufC;
        const int*   oidx = (l == 0) ? nullptr : (l == 1 ? oidxA : oidxB);
        int* oidxN        = (l == 0) ? oidxA : oidxB;

        k_alar<<<n / 4, 256, 0, stream>>>(cur, att_l + l * C, att_r + l * C,
                                          al, ar, degI, score, keep, nmap, n);
        k_degscore<<<(NEDGE + 255) / 256, 256, 0, stream>>>(srcA, dstA, emask, degI, score);
        k_selfco<<<(n + 255) / 256, 256, 0, stream>>>(degI, al, ar, dinv, selfco, n);

        int nblk = n / 2048;
        k_scan1<<<nblk, 256, 0, stream>>>(degI, rowptr, bsum);
        k_scan2<<<1, 64, 0, stream>>>(bsum, nblk);
        k_scan3<<<n / 256, 256, 0, stream>>>(rowptr, cursor, bsum, n);

        k_fill<<<(NEDGE + 255) / 256, 256, 0, stream>>>(srcA, dstA, emask, dinv, al, ar,
                                                        cursor, srcE, cfE);
        k_msg_csr<<<n / 4, 256, 0, stream>>>(rowptr, degI, srcE, cfE, cur, x, oidx,
                                             selfco, bufH, n);
        k_pool<<<dim3(G, npg / 256), 128, 0, stream>>>(bufH, pooled, npg, l);

        if (l < 2) {
            k_topk<<<G, 256, 0, stream>>>(score, npg, k, keep, nmap, perm);
            int m = G * k;
            k_gather<<<(m * 32 + 255) / 256, 256, 0, stream>>>(bufH, perm, oidx, bufC, oidxN, m);
            k_remap<<<(NEDGE + 255) / 256, 256, 0, stream>>>(srcA, dstA, emask, keep, nmap);
        }
    }

    k_tail<<<G, 256, 0, stream>>>(pooled, w_ih, b_ih, b_hh, w_fin, b_fin,
                                  w_root, b_root, rootv, alphap, out);
}

// Round 3
// 851.698 us; speedup vs baseline: 2.5527x; 1.3555x over previous
//
#include <hip/hip_runtime.h>
#include <math.h>

#define G 8
#define N0 16384
#define NEDGE (G*N0*8)      // 1048576
#define C 128
#define EPS_FA 0.1f
#define SMAX 2048

// ---------------- init ----------------
__global__ void k_init_edges(const int* __restrict__ ei, int* __restrict__ srcA,
                             int* __restrict__ dstA, unsigned char* __restrict__ em) {
    int e = blockIdx.x * 256 + threadIdx.x;
    if (e < NEDGE) { srcA[e] = ei[e]; dstA[e] = ei[NEDGE + e]; em[e] = 1; }
}

__global__ void k_zero_pooled(float* p) {
    int i = blockIdx.x * 256 + threadIdx.x;
    if (i < G * 384) p[i] = 0.0f;
}

// ---------------- per-node attention dots + zero scratch ----------------
__global__ void k_alar(const float* __restrict__ cur,
                       const float* __restrict__ attl, const float* __restrict__ attr,
                       float* __restrict__ al, float* __restrict__ ar,
                       int* __restrict__ degI, int* __restrict__ score,
                       unsigned char* __restrict__ keep, int* __restrict__ nmap, int n) {
    int wid  = (blockIdx.x * blockDim.x + threadIdx.x) >> 6;
    int lane = threadIdx.x & 63;
    if (wid >= n) return;
    float2 v  = ((const float2*)(cur + (size_t)wid * C))[lane];
    float2 l2 = ((const float2*)attl)[lane];
    float2 r2 = ((const float2*)attr)[lane];
    float sl = v.x * l2.x + v.y * l2.y;
    float sr = v.x * r2.x + v.y * r2.y;
    for (int o = 32; o >= 1; o >>= 1) { sl += __shfl_xor(sl, o); sr += __shfl_xor(sr, o); }
    if (lane == 0) {
        al[wid] = sl; ar[wid] = sr;
        degI[wid] = 0; score[wid] = 0; keep[wid] = 0; nmap[wid] = 0;
    }
}

// ---------------- degree / score accumulation ----------------
__global__ void k_degscore(const int* __restrict__ src, const int* __restrict__ dst,
                           const unsigned char* __restrict__ em,
                           int* __restrict__ degI, int* __restrict__ score) {
    int e = blockIdx.x * 256 + threadIdx.x;
    if (e >= NEDGE) return;
    if (em[e]) { atomicAdd(&degI[dst[e]], 1); atomicAdd(&score[src[e]], 1); }
}

// ---------------- dinv + self-loop coefficient ----------------
__global__ void k_selfco(const int* __restrict__ degI, const float* __restrict__ al,
                         const float* __restrict__ ar, float* __restrict__ dinv,
                         float* __restrict__ selfco, int n) {
    int v = blockIdx.x * 256 + threadIdx.x;
    if (v >= n) return;
    float d  = (float)degI[v] + 1.0f;
    float di = rsqrtf(d);
    dinv[v]   = di;
    selfco[v] = di * di * tanhf(al[v] + ar[v]);
}

// ---------------- prefix scan: degI -> rowptr (exclusive), cursor copy ----------------
__global__ void __launch_bounds__(256) k_scan1(const int* __restrict__ degI,
                                               int* __restrict__ rowptr,
                                               int* __restrict__ bsum) {
    __shared__ int part[256];
    int t = threadIdx.x;
    int base = blockIdx.x * 2048 + t * 8;
    int v[8]; int s = 0;
    for (int i = 0; i < 8; i++) { v[i] = degI[base + i]; s += v[i]; }
    part[t] = s; __syncthreads();
    for (int o = 1; o < 256; o <<= 1) {
        int val = part[t];
        int add = (t >= o) ? part[t - o] : 0;
        __syncthreads();
        part[t] = val + add;
        __syncthreads();
    }
    int run = (t == 0) ? 0 : part[t - 1];
    if (t == 255) bsum[blockIdx.x] = part[255];
    for (int i = 0; i < 8; i++) { rowptr[base + i] = run; run += v[i]; }
}

__global__ void k_scan2(int* __restrict__ bsum, int nb) {
    if (threadIdx.x == 0 && blockIdx.x == 0) {
        int acc = 0;
        for (int i = 0; i < nb; i++) { int v = bsum[i]; bsum[i] = acc; acc += v; }
    }
}

__global__ void k_scan3(int* __restrict__ rowptr, int* __restrict__ cursor,
                        const int* __restrict__ bsum, int n) {
    int i = blockIdx.x * 256 + threadIdx.x;
    if (i >= n) return;
    int v = rowptr[i] + bsum[i >> 11];
    rowptr[i] = v; cursor[i] = v;
}

// ---------------- fill CSR (coef computed inline) ----------------
__global__ void k_fill(const int* __restrict__ src, const int* __restrict__ dst,
                       const unsigned char* __restrict__ em,
                       const float* __restrict__ dinv, const float* __restrict__ al,
                       const float* __restrict__ ar,
                       int* __restrict__ cursor, int* __restrict__ srcE,
                       float* __restrict__ cfE) {
    int e = blockIdx.x * 256 + threadIdx.x;
    if (e >= NEDGE) return;
    if (!em[e]) return;
    int s = src[e], d = dst[e];
    float cf = dinv[s] * dinv[d] * tanhf(al[d] + ar[s]);
    int pos = atomicAdd(&cursor[d], 1);
    srcE[pos] = s; cfE[pos] = cf;
}

// ---------------- CSR gather messages: one wave per dst node ----------------
__global__ void k_msg_csr(const int* __restrict__ rowptr, const int* __restrict__ degI,
                          const int* __restrict__ srcE, const float* __restrict__ cfE,
                          const float* __restrict__ cur, const float* __restrict__ x,
                          const int* __restrict__ oidx, const float* __restrict__ selfco,
                          float* __restrict__ h, int n) {
    int wid  = (blockIdx.x * blockDim.x + threadIdx.x) >> 6;
    int lane = threadIdx.x & 63;
    if (wid >= n) return;
    int rs = rowptr[wid], deg = degI[wid];
    float accx = 0.0f, accy = 0.0f;
    for (int j = rs; j < rs + deg; j++) {
        int s = srcE[j];
        float cf = cfE[j];
        float2 v = ((const float2*)(cur + (size_t)s * C))[lane];
        accx += cf * v.x; accy += cf * v.y;
    }
    int o = oidx ? oidx[wid] : wid;
    float2 cv = ((const float2*)(cur + (size_t)wid * C))[lane];
    float2 xv = ((const float2*)(x   + (size_t)o   * C))[lane];
    float sc = selfco[wid];
    float2 r;
    r.x = fmaxf(accx + sc * cv.x + EPS_FA * xv.x, 0.0f);
    r.y = fmaxf(accy + sc * cv.y + EPS_FA * xv.y, 0.0f);
    ((float2*)(h + (size_t)wid * C))[lane] = r;
}

// ---------------- per-graph max pool (h already relu'd) ----------------
__global__ void k_pool(const float* __restrict__ h, float* __restrict__ pooled,
                       int npg, int layer) {
    int g = blockIdx.x, chunk = blockIdx.y, c = threadIdx.x;
    int r0 = chunk * 256;
    float m = 0.0f;
    const float* base = h + ((size_t)g * npg + r0) * C + c;
    for (int r = 0; r < 256; r++) m = fmaxf(m, base[(size_t)r * C]);
    atomicMax((unsigned int*)&pooled[g * 384 + layer * 128 + c], __float_as_uint(m));
}

// ---------------- parallel exact stable top-k ----------------
// pos(v) = basepos[g][s] + blockoff[g][b][s] + local_rank(v in chunk b)
__global__ void __launch_bounds__(256) k_hist(const int* __restrict__ score, int npg, int nb,
                                              int* __restrict__ blockhist) {
    __shared__ int lh[SMAX];
    int g = blockIdx.x / nb, b = blockIdx.x % nb, t = threadIdx.x;
    for (int s = t; s < SMAX; s += 256) lh[s] = 0;
    __syncthreads();
    int s = score[g * npg + b * 256 + t];
    if (s > SMAX - 1) s = SMAX - 1;
    atomicAdd(&lh[s], 1);
    __syncthreads();
    int* outp = blockhist + ((size_t)g * nb + b) * SMAX;
    for (int i = t; i < SMAX; i += 256) outp[i] = lh[i];
}

// exclusive prefix across chunks per (g, s); total into hist[g][s]
__global__ void k_binprefix(int* __restrict__ blockhist, int* __restrict__ hist, int nb) {
    int g = blockIdx.x >> 3;                      // SMAX/256 == 8 chunks of bins
    int s = (blockIdx.x & 7) * 256 + threadIdx.x;
    int* base = blockhist + (size_t)g * nb * SMAX + s;
    int acc = 0;
    for (int b = 0; b < nb; b++) {
        int v = base[(size_t)b * SMAX];
        base[(size_t)b * SMAX] = acc;
        acc += v;
    }
    hist[g * SMAX + s] = acc;
}

// basepos[g][s] = # nodes with score > s  (descending exclusive scan over bins)
__global__ void __launch_bounds__(256) k_basepos(const int* __restrict__ hist,
                                                 int* __restrict__ basepos) {
    __shared__ int part[256];
    int g = blockIdx.x, t = threadIdx.x;
    const int* hg = hist + g * SMAX;
    int* bp = basepos + g * SMAX;
    int v[8]; int s = 0;
    for (int i = 0; i < 8; i++) { v[i] = hg[SMAX - 1 - (t * 8 + i)]; s += v[i]; }
    part[t] = s; __syncthreads();
    for (int o = 1; o < 256; o <<= 1) {
        int val = part[t];
        int add = (t >= o) ? part[t - o] : 0;
        __syncthreads();
        part[t] = val + add;
        __syncthreads();
    }
    int run = (t == 0) ? 0 : part[t - 1];
    for (int i = 0; i < 8; i++) { bp[SMAX - 1 - (t * 8 + i)] = run; run += v[i]; }
}

__global__ void __launch_bounds__(256) k_rank(const int* __restrict__ score,
                                              const int* __restrict__ blockhist,
                                              const int* __restrict__ basepos,
                                              int npg, int nb, int k,
                                              unsigned char* __restrict__ keep,
                                              int* __restrict__ nmap, int* __restrict__ perm) {
    __shared__ int cs[256];
    int g = blockIdx.x / nb, b = blockIdx.x % nb, t = threadIdx.x;
    int v = b * 256 + t;
    int s = score[g * npg + v];
    if (s > SMAX - 1) s = SMAX - 1;
    cs[t] = s;
    __syncthreads();
    int cnt = 0;
    for (int u = 0; u < t; u++) cnt += (cs[u] == s);   // broadcast reads
    int pos = basepos[g * SMAX + s]
            + blockhist[((size_t)g * nb + b) * SMAX + s]
            + cnt;
    if (pos < k) {
        int vg = g * npg + v;
        int nid = g * k + pos;
        keep[vg] = 1; nmap[vg] = nid; perm[nid] = vg;
    }
}

// ---------------- gather kept nodes + oidx chain ----------------
__global__ void k_gather(const float* __restrict__ h, const int* __restrict__ perm,
                         const int* __restrict__ oidx, float* __restrict__ curN,
                         int* __restrict__ oidxN, int m) {
    int i = blockIdx.x * 256 + threadIdx.x;
    if (i >= m * 32) return;
    int j = i >> 5, c4 = i & 31;
    int p = perm[j];
    float4 v = ((const float4*)(h + (size_t)p * C))[c4];
    ((float4*)(curN + (size_t)j * C))[c4] = v;
    if (c4 == 0) oidxN[j] = oidx ? oidx[p] : p;
}

// ---------------- remap edges in place ----------------
__global__ void k_remap(int* __restrict__ src, int* __restrict__ dst,
                        unsigned char* __restrict__ em,
                        const unsigned char* __restrict__ keep, const int* __restrict__ nmap) {
    int e = blockIdx.x * 256 + threadIdx.x;
    if (e >= NEDGE) return;
    int s = src[e], d = dst[e];
    if (em[e] && keep[s] && keep[d]) { src[e] = nmap[s]; dst[e] = nmap[d]; }
    else { em[e] = 0; src[e] = 0; dst[e] = 0; }
}

// ---------------- GRU + final linears ----------------
__global__ void __launch_bounds__(256) k_tail(const float* __restrict__ pooled,
        const float* __restrict__ wih, const float* __restrict__ bih,
        const float* __restrict__ bhh, const float* __restrict__ wfin,
        const float* __restrict__ bfin, const float* __restrict__ wroot,
        const float* __restrict__ broot, const float* __restrict__ rootv,
        const float* __restrict__ alphap, float* __restrict__ out) {
    int g = blockIdx.x, t = threadIdx.x;
    __shared__ float fused[384];
    __shared__ float gi[768];
    __shared__ float hg[256];
    for (int j = t; j < 384; j += 256) fused[j] = pooled[g * 384 + j];
    __syncthreads();
    for (int r = t; r < 768; r += 256) {
        float s = bih[r];
        const float* w = wih + (size_t)r * 384;
        for (int j = 0; j < 384; j++) s += w[j] * fused[j];
        gi[r] = s;
    }
    __syncthreads();
    if (t < 256) {
        float r  = 1.0f / (1.0f + expf(-(gi[t]       + bhh[t])));
        float z  = 1.0f / (1.0f + expf(-(gi[256 + t] + bhh[256 + t])));
        float nc = tanhf(gi[512 + t] + r * bhh[512 + t]);
        hg[t] = (1.0f - z) * nc;
    }
    __syncthreads();
    if (t < 128) {
        float o = bfin[t];
        const float* w = wfin + (size_t)t * 256;
        for (int j = 0; j < 256; j++) o += w[j] * hg[j];
        float re = broot[t];
        const float* wr = wroot + (size_t)t * 128;
        const float* rg = rootv + (size_t)g * 128;
        for (int j = 0; j < 128; j++) re += wr[j] * rg[j];
        float a = alphap[0];
        out[g * 128 + t] = a * o + (1.0f - a) * re;
    }
}

extern "C" void kernel_launch(void* const* d_in, const int* in_sizes, int n_in,
                              void* d_out, int out_size, void* d_ws, size_t ws_size,
                              hipStream_t stream) {
    const float* x      = (const float*)d_in[0];
    const int*   ei     = (const int*)d_in[1];
    const float* rootv  = (const float*)d_in[3];
    const float* att_l  = (const float*)d_in[4];
    const float* att_r  = (const float*)d_in[5];
    const float* w_ih   = (const float*)d_in[6];
    const float* b_ih   = (const float*)d_in[8];
    const float* b_hh   = (const float*)d_in[9];
    const float* w_fin  = (const float*)d_in[10];
    const float* b_fin  = (const float*)d_in[11];
    const float* w_root = (const float*)d_in[12];
    const float* b_root = (const float*)d_in[13];
    const float* alphap = (const float*)d_in[14];
    float* out = (float*)d_out;

    char* wsb = (char*)d_ws;
    size_t off = 0;
    auto alloc = [&](size_t bytes) -> char* {
        char* p = wsb + off; off += (bytes + 255) & ~(size_t)255; return p;
    };
    float* bufH   = (float*)alloc((size_t)131072 * C * 4);
    float* bufC   = (float*)alloc((size_t)65536  * C * 4);
    int*   srcA   = (int*)alloc((size_t)NEDGE * 4);
    int*   dstA   = (int*)alloc((size_t)NEDGE * 4);
    unsigned char* emask = (unsigned char*)alloc(NEDGE);
    int*   srcE   = (int*)alloc((size_t)NEDGE * 4);
    float* cfE    = (float*)alloc((size_t)NEDGE * 4);
    float* al     = (float*)alloc(131072 * 4);
    float* ar     = (float*)alloc(131072 * 4);
    float* dinv   = (float*)alloc(131072 * 4);
    float* selfco = (float*)alloc(131072 * 4);
    int*   degI   = (int*)alloc(131072 * 4);
    int*   score  = (int*)alloc(131072 * 4);
    int*   rowptr = (int*)alloc(131072 * 4);
    int*   cursor = (int*)alloc(131072 * 4);
    int*   bsum   = (int*)alloc(256 * 4);
    unsigned char* keep = (unsigned char*)alloc(131072);
    int*   nmap   = (int*)alloc(131072 * 4);
    int*   perm   = (int*)alloc(65536 * 4);
    int*   oidxA  = (int*)alloc(65536 * 4);
    int*   oidxB  = (int*)alloc(32768 * 4);
    float* pooled = (float*)alloc(G * 384 * 4);
    int*   blockhist = (int*)alloc((size_t)G * 64 * SMAX * 4);  // 4 MB
    int*   histT  = (int*)alloc((size_t)G * SMAX * 4);
    int*   baseposT = (int*)alloc((size_t)G * SMAX * 4);

    k_init_edges<<<(NEDGE + 255) / 256, 256, 0, stream>>>(ei, srcA, dstA, emask);
    k_zero_pooled<<<(G * 384 + 255) / 256, 256, 0, stream>>>(pooled);

    const int ns[3]   = {131072, 65536, 32768};
    const int npgs[3] = {16384, 8192, 4096};
    const int ks[3]   = {8192, 4096, 0};

    for (int l = 0; l < 3; l++) {
        int n = ns[l], npg = npgs[l], k = ks[l];
        const float* cur  = (l == 0) ? x : bufC;
        const int*   oidx = (l == 0) ? nullptr : (l == 1 ? oidxA : oidxB);
        int* oidxN        = (l == 0) ? oidxA : oidxB;

        k_alar<<<n / 4, 256, 0, stream>>>(cur, att_l + l * C, att_r + l * C,
                                          al, ar, degI, score, keep, nmap, n);
        k_degscore<<<(NEDGE + 255) / 256, 256, 0, stream>>>(srcA, dstA, emask, degI, score);
        k_selfco<<<(n + 255) / 256, 256, 0, stream>>>(degI, al, ar, dinv, selfco, n);

        int nblk = n / 2048;
        k_scan1<<<nblk, 256, 0, stream>>>(degI, rowptr, bsum);
        k_scan2<<<1, 64, 0, stream>>>(bsum, nblk);
        k_scan3<<<n / 256, 256, 0, stream>>>(rowptr, cursor, bsum, n);

        k_fill<<<(NEDGE + 255) / 256, 256, 0, stream>>>(srcA, dstA, emask, dinv, al, ar,
                                                        cursor, srcE, cfE);
        k_msg_csr<<<n / 4, 256, 0, stream>>>(rowptr, degI, srcE, cfE, cur, x, oidx,
                                             selfco, bufH, n);
        k_pool<<<dim3(G, npg / 256), 128, 0, stream>>>(bufH, pooled, npg, l);

        if (l < 2) {
            int nb = npg / 256;
            k_hist<<<G * nb, 256, 0, stream>>>(score, npg, nb, blockhist);
            k_binprefix<<<G * 8, 256, 0, stream>>>(blockhist, histT, nb);
            k_basepos<<<G, 256, 0, stream>>>(histT, baseposT);
            k_rank<<<G * nb, 256, 0, stream>>>(score, blockhist, baseposT, npg, nb, k,
                                               keep, nmap, perm);
            int m = G * k;
            k_gather<<<(m * 32 + 255) / 256, 256, 0, stream>>>(bufH, perm, oidx, bufC, oidxN, m);
            k_remap<<<(NEDGE + 255) / 256, 256, 0, stream>>>(srcA, dstA, emask, keep, nmap);
        }
    }

    k_tail<<<G, 256, 0, stream>>>(pooled, w_ih, b_ih, b_hh, w_fin, b_fin,
                                  w_root, b_root, rootv, alphap, out);
}

// Round 4
// 742.650 us; speedup vs baseline: 2.9275x; 1.1468x over previous
//
#include <hip/hip_runtime.h>
#include <math.h>

#define G 8
#define N0 16384
#define NEDGE (G*N0*8)      // 1048576
#define C 128
#define EPS_FA 0.1f
#define SMAX 2048

// ---------------- zero pooled + layer-0 degI/score ----------------
__global__ void k_zeroL0(float* __restrict__ pooled, int* __restrict__ degI,
                         int* __restrict__ score) {
    int i = blockIdx.x * 256 + threadIdx.x;
    if (i < 131072) { degI[i] = 0; score[i] = 0; }
    if (i < G * 384) pooled[i] = 0.0f;
}

// ---------------- init edges + degree/score (fused) ----------------
__global__ void k_init_edges_deg(const int* __restrict__ ei, int* __restrict__ srcA,
                                 int* __restrict__ dstA, unsigned char* __restrict__ em,
                                 int* __restrict__ degI, int* __restrict__ score) {
    int e = blockIdx.x * 256 + threadIdx.x;
    if (e >= NEDGE) return;
    int s = ei[e], d = ei[NEDGE + e];
    srcA[e] = s; dstA[e] = d; em[e] = 1;
    atomicAdd(&degI[d], 1); atomicAdd(&score[s], 1);
}

// ---------------- layer-0 attention dots ----------------
__global__ void k_alar(const float* __restrict__ cur,
                       const float* __restrict__ attl, const float* __restrict__ attr,
                       float* __restrict__ al, float* __restrict__ ar, int n) {
    int wid  = (blockIdx.x * blockDim.x + threadIdx.x) >> 6;
    int lane = threadIdx.x & 63;
    if (wid >= n) return;
    float2 v  = ((const float2*)(cur + (size_t)wid * C))[lane];
    float2 l2 = ((const float2*)attl)[lane];
    float2 r2 = ((const float2*)attr)[lane];
    float sl = v.x * l2.x + v.y * l2.y;
    float sr = v.x * r2.x + v.y * r2.y;
    for (int o = 32; o >= 1; o >>= 1) { sl += __shfl_xor(sl, o); sr += __shfl_xor(sr, o); }
    if (lane == 0) { al[wid] = sl; ar[wid] = sr; }
}

// ---------------- prefix scan: degI -> rowptr (exclusive) ----------------
__global__ void __launch_bounds__(256) k_scan1(const int* __restrict__ degI,
                                               int* __restrict__ rowptr,
                                               int* __restrict__ bsum) {
    __shared__ int part[256];
    int t = threadIdx.x;
    int base = blockIdx.x * 2048 + t * 8;
    int v[8]; int s = 0;
    for (int i = 0; i < 8; i++) { v[i] = degI[base + i]; s += v[i]; }
    part[t] = s; __syncthreads();
    for (int o = 1; o < 256; o <<= 1) {
        int val = part[t];
        int add = (t >= o) ? part[t - o] : 0;
        __syncthreads();
        part[t] = val + add;
        __syncthreads();
    }
    int run = (t == 0) ? 0 : part[t - 1];
    if (t == 255) bsum[blockIdx.x] = part[255];
    for (int i = 0; i < 8; i++) { rowptr[base + i] = run; run += v[i]; }
}

__global__ void k_scan2(int* __restrict__ bsum, int nb) {
    if (threadIdx.x == 0 && blockIdx.x == 0) {
        int acc = 0;
        for (int i = 0; i < nb; i++) { int v = bsum[i]; bsum[i] = acc; acc += v; }
    }
}

// scan3 + selfco + keep/nmap zero (fused per-node pass)
__global__ void k_scan3s(int* __restrict__ rowptr, int* __restrict__ cursor,
                         const int* __restrict__ bsum, const int* __restrict__ degI,
                         const float* __restrict__ al, const float* __restrict__ ar,
                         float* __restrict__ dinv, float* __restrict__ selfco,
                         unsigned char* __restrict__ keep, int* __restrict__ nmap, int n) {
    int i = blockIdx.x * 256 + threadIdx.x;
    if (i >= n) return;
    int v = rowptr[i] + bsum[i >> 11];
    rowptr[i] = v; cursor[i] = v;
    float d  = (float)degI[i] + 1.0f;
    float di = rsqrtf(d);
    dinv[i]   = di;
    selfco[i] = di * di * tanhf(al[i] + ar[i]);
    keep[i] = 0; nmap[i] = 0;
}

// ---------------- fill CSR: packed (src, coef) records ----------------
__global__ void k_fill(const int* __restrict__ src, const int* __restrict__ dst,
                       const unsigned char* __restrict__ em,
                       const float* __restrict__ dinv, const float* __restrict__ al,
                       const float* __restrict__ ar,
                       int* __restrict__ cursor, int2* __restrict__ edges) {
    int e = blockIdx.x * 256 + threadIdx.x;
    if (e >= NEDGE) return;
    if (!em[e]) return;
    int s = src[e], d = dst[e];
    float cf = dinv[s] * dinv[d] * tanhf(al[d] + ar[s]);
    int pos = atomicAdd(&cursor[d], 1);
    edges[pos] = make_int2(s, __float_as_int(cf));
}

// ---------------- CSR gather messages: half-wave per dst node, XCD swizzle ----
// block = 8 nodes (8 half-waves); blockIdx&7 selects graph -> XCD L2 affinity
__global__ void __launch_bounds__(256) k_msg_csr(
        const int* __restrict__ rowptr, const int* __restrict__ degI,
        const int2* __restrict__ edges,
        const float* __restrict__ cur, const float* __restrict__ x,
        const int* __restrict__ oidx, const float* __restrict__ selfco,
        float* __restrict__ h, int npg) {
    int g    = blockIdx.x & 7;
    int ib   = blockIdx.x >> 3;
    int sub  = threadIdx.x >> 5;     // half-wave id 0..7
    int lane = threadIdx.x & 31;
    int v = g * npg + ib * 8 + sub;
    int rs = rowptr[v], deg = degI[v];
    float ax = 0.0f, ay = 0.0f, az = 0.0f, aw = 0.0f;
    for (int j = 0; j < deg; j++) {
        int2 er = edges[rs + j];
        float cf = __int_as_float(er.y);
        float4 t = ((const float4*)(cur + (size_t)er.x * C))[lane];
        ax += cf * t.x; ay += cf * t.y; az += cf * t.z; aw += cf * t.w;
    }
    int o = oidx ? oidx[v] : v;
    float4 cv = ((const float4*)(cur + (size_t)v * C))[lane];
    float4 xv = ((const float4*)(x   + (size_t)o * C))[lane];
    float sc = selfco[v];
    float4 r;
    r.x = fmaxf(ax + sc * cv.x + EPS_FA * xv.x, 0.0f);
    r.y = fmaxf(ay + sc * cv.y + EPS_FA * xv.y, 0.0f);
    r.z = fmaxf(az + sc * cv.z + EPS_FA * xv.z, 0.0f);
    r.w = fmaxf(aw + sc * cv.w + EPS_FA * xv.w, 0.0f);
    ((float4*)(h + (size_t)v * C))[lane] = r;
}

// ---------------- per-graph max pool (h already relu'd) ----------------
__global__ void k_pool(const float* __restrict__ h, float* __restrict__ pooled,
                       int npg, int layer) {
    int g = blockIdx.x, chunk = blockIdx.y, c = threadIdx.x;
    int r0 = chunk * 256;
    float m = 0.0f;
    const float* base = h + ((size_t)g * npg + r0) * C + c;
    for (int r = 0; r < 256; r++) m = fmaxf(m, base[(size_t)r * C]);
    atomicMax((unsigned int*)&pooled[g * 384 + layer * 128 + c], __float_as_uint(m));
}

// ---------------- parallel exact stable top-k ----------------
__global__ void __launch_bounds__(256) k_hist(const int* __restrict__ score, int npg, int nb,
                                              int* __restrict__ blockhist) {
    __shared__ int lh[SMAX];
    int g = blockIdx.x / nb, b = blockIdx.x % nb, t = threadIdx.x;
    for (int s = t; s < SMAX; s += 256) lh[s] = 0;
    __syncthreads();
    int s = score[g * npg + b * 256 + t];
    if (s > SMAX - 1) s = SMAX - 1;
    atomicAdd(&lh[s], 1);
    __syncthreads();
    int* outp = blockhist + ((size_t)g * nb + b) * SMAX;
    for (int i = t; i < SMAX; i += 256) outp[i] = lh[i];
}

__global__ void k_binprefix(int* __restrict__ blockhist, int* __restrict__ hist, int nb) {
    int g = blockIdx.x >> 3;
    int s = (blockIdx.x & 7) * 256 + threadIdx.x;
    int* base = blockhist + (size_t)g * nb * SMAX + s;
    int acc = 0;
    for (int b = 0; b < nb; b++) {
        int v = base[(size_t)b * SMAX];
        base[(size_t)b * SMAX] = acc;
        acc += v;
    }
    hist[g * SMAX + s] = acc;
}

__global__ void __launch_bounds__(256) k_basepos(const int* __restrict__ hist,
                                                 int* __restrict__ basepos) {
    __shared__ int part[256];
    int g = blockIdx.x, t = threadIdx.x;
    const int* hg = hist + g * SMAX;
    int* bp = basepos + g * SMAX;
    int v[8]; int s = 0;
    for (int i = 0; i < 8; i++) { v[i] = hg[SMAX - 1 - (t * 8 + i)]; s += v[i]; }
    part[t] = s; __syncthreads();
    for (int o = 1; o < 256; o <<= 1) {
        int val = part[t];
        int add = (t >= o) ? part[t - o] : 0;
        __syncthreads();
        part[t] = val + add;
        __syncthreads();
    }
    int run = (t == 0) ? 0 : part[t - 1];
    for (int i = 0; i < 8; i++) { bp[SMAX - 1 - (t * 8 + i)] = run; run += v[i]; }
}

__global__ void __launch_bounds__(256) k_rank(const int* __restrict__ score,
                                              const int* __restrict__ blockhist,
                                              const int* __restrict__ basepos,
                                              int npg, int nb, int k,
                                              unsigned char* __restrict__ keep,
                                              int* __restrict__ nmap, int* __restrict__ perm) {
    __shared__ int cs[256];
    int g = blockIdx.x / nb, b = blockIdx.x % nb, t = threadIdx.x;
    int v = b * 256 + t;
    int s = score[g * npg + v];
    if (s > SMAX - 1) s = SMAX - 1;
    cs[t] = s;
    __syncthreads();
    int cnt = 0;
    for (int u = 0; u < t; u++) cnt += (cs[u] == s);
    int pos = basepos[g * SMAX + s]
            + blockhist[((size_t)g * nb + b) * SMAX + s]
            + cnt;
    if (pos < k) {
        int vg = g * npg + v;
        int nid = g * k + pos;
        keep[vg] = 1; nmap[vg] = nid; perm[nid] = vg;
    }
}

// ---------------- gather kept nodes + next-layer al/ar + zero next degI/score ----
__global__ void k_gather_alar(const float* __restrict__ h, const int* __restrict__ perm,
                              const int* __restrict__ oidx,
                              const float* __restrict__ attlN, const float* __restrict__ attrN,
                              float* __restrict__ curN, int* __restrict__ oidxN,
                              float* __restrict__ al, float* __restrict__ ar,
                              int* __restrict__ degI, int* __restrict__ score, int m) {
    int i = blockIdx.x * 256 + threadIdx.x;
    if (i >= m * 32) return;
    int j = i >> 5, c4 = i & 31;
    int p = perm[j];
    float4 v = ((const float4*)(h + (size_t)p * C))[c4];
    ((float4*)(curN + (size_t)j * C))[c4] = v;
    float4 l4 = ((const float4*)attlN)[c4];
    float4 r4 = ((const float4*)attrN)[c4];
    float sl = v.x * l4.x + v.y * l4.y + v.z * l4.z + v.w * l4.w;
    float sr = v.x * r4.x + v.y * r4.y + v.z * r4.z + v.w * r4.w;
    for (int o = 16; o >= 1; o >>= 1) { sl += __shfl_xor(sl, o); sr += __shfl_xor(sr, o); }
    if (c4 == 0) {
        al[j] = sl; ar[j] = sr;
        oidxN[j] = oidx ? oidx[p] : p;
        degI[j] = 0; score[j] = 0;
    }
}

// ---------------- remap edges + next-layer degree/score (fused) ----------------
__global__ void k_remap_deg(int* __restrict__ src, int* __restrict__ dst,
                            unsigned char* __restrict__ em,
                            const unsigned char* __restrict__ keep, const int* __restrict__ nmap,
                            int* __restrict__ degI, int* __restrict__ score) {
    int e = blockIdx.x * 256 + threadIdx.x;
    if (e >= NEDGE) return;
    int s = src[e], d = dst[e];
    if (em[e] && keep[s] && keep[d]) {
        int ns = nmap[s], nd = nmap[d];
        src[e] = ns; dst[e] = nd;
        atomicAdd(&degI[nd], 1); atomicAdd(&score[ns], 1);
    } else { em[e] = 0; src[e] = 0; dst[e] = 0; }
}

// ---------------- GRU + final linears ----------------
__global__ void __launch_bounds__(256) k_tail(const float* __restrict__ pooled,
        const float* __restrict__ wih, const float* __restrict__ bih,
        const float* __restrict__ bhh, const float* __restrict__ wfin,
        const float* __restrict__ bfin, const float* __restrict__ wroot,
        const float* __restrict__ broot, const float* __restrict__ rootv,
        const float* __restrict__ alphap, float* __restrict__ out) {
    int g = blockIdx.x, t = threadIdx.x;
    __shared__ float fused[384];
    __shared__ float gi[768];
    __shared__ float hg[256];
    for (int j = t; j < 384; j += 256) fused[j] = pooled[g * 384 + j];
    __syncthreads();
    for (int r = t; r < 768; r += 256) {
        float s = bih[r];
        const float* w = wih + (size_t)r * 384;
        for (int j = 0; j < 384; j++) s += w[j] * fused[j];
        gi[r] = s;
    }
    __syncthreads();
    if (t < 256) {
        float r  = 1.0f / (1.0f + expf(-(gi[t]       + bhh[t])));
        float z  = 1.0f / (1.0f + expf(-(gi[256 + t] + bhh[256 + t])));
        float nc = tanhf(gi[512 + t] + r * bhh[512 + t]);
        hg[t] = (1.0f - z) * nc;
    }
    __syncthreads();
    if (t < 128) {
        float o = bfin[t];
        const float* w = wfin + (size_t)t * 256;
        for (int j = 0; j < 256; j++) o += w[j] * hg[j];
        float re = broot[t];
        const float* wr = wroot + (size_t)t * 128;
        const float* rg = rootv + (size_t)g * 128;
        for (int j = 0; j < 128; j++) re += wr[j] * rg[j];
        float a = alphap[0];
        out[g * 128 + t] = a * o + (1.0f - a) * re;
    }
}

extern "C" void kernel_launch(void* const* d_in, const int* in_sizes, int n_in,
                              void* d_out, int out_size, void* d_ws, size_t ws_size,
                              hipStream_t stream) {
    const float* x      = (const float*)d_in[0];
    const int*   ei     = (const int*)d_in[1];
    const float* rootv  = (const float*)d_in[3];
    const float* att_l  = (const float*)d_in[4];
    const float* att_r  = (const float*)d_in[5];
    const float* w_ih   = (const float*)d_in[6];
    const float* b_ih   = (const float*)d_in[8];
    const float* b_hh   = (const float*)d_in[9];
    const float* w_fin  = (const float*)d_in[10];
    const float* b_fin  = (const float*)d_in[11];
    const float* w_root = (const float*)d_in[12];
    const float* b_root = (const float*)d_in[13];
    const float* alphap = (const float*)d_in[14];
    float* out = (float*)d_out;

    char* wsb = (char*)d_ws;
    size_t off = 0;
    auto alloc = [&](size_t bytes) -> char* {
        char* p = wsb + off; off += (bytes + 255) & ~(size_t)255; return p;
    };
    float* bufH   = (float*)alloc((size_t)131072 * C * 4);
    float* bufC   = (float*)alloc((size_t)65536  * C * 4);
    int*   srcA   = (int*)alloc((size_t)NEDGE * 4);
    int*   dstA   = (int*)alloc((size_t)NEDGE * 4);
    unsigned char* emask = (unsigned char*)alloc(NEDGE);
    int2*  edges  = (int2*)alloc((size_t)NEDGE * 8);
    float* al     = (float*)alloc(131072 * 4);
    float* ar     = (float*)alloc(131072 * 4);
    float* dinv   = (float*)alloc(131072 * 4);
    float* selfco = (float*)alloc(131072 * 4);
    int*   degI   = (int*)alloc(131072 * 4);
    int*   score  = (int*)alloc(131072 * 4);
    int*   rowptr = (int*)alloc(131072 * 4);
    int*   cursor = (int*)alloc(131072 * 4);
    int*   bsum   = (int*)alloc(256 * 4);
    unsigned char* keep = (unsigned char*)alloc(131072);
    int*   nmap   = (int*)alloc(131072 * 4);
    int*   perm   = (int*)alloc(65536 * 4);
    int*   oidxA  = (int*)alloc(65536 * 4);
    int*   oidxB  = (int*)alloc(32768 * 4);
    float* pooled = (float*)alloc(G * 384 * 4);
    int*   blockhist = (int*)alloc((size_t)G * 64 * SMAX * 4);
    int*   histT  = (int*)alloc((size_t)G * SMAX * 4);
    int*   baseposT = (int*)alloc((size_t)G * SMAX * 4);

    k_zeroL0<<<512, 256, 0, stream>>>(pooled, degI, score);
    k_init_edges_deg<<<(NEDGE + 255) / 256, 256, 0, stream>>>(ei, srcA, dstA, emask,
                                                              degI, score);

    const int ns[3]   = {131072, 65536, 32768};
    const int npgs[3] = {16384, 8192, 4096};
    const int ks[3]   = {8192, 4096, 0};

    for (int l = 0; l < 3; l++) {
        int n = ns[l], npg = npgs[l], k = ks[l];
        const float* cur  = (l == 0) ? x : bufC;
        const int*   oidx = (l == 0) ? nullptr : (l == 1 ? oidxA : oidxB);
        int* oidxN        = (l == 0) ? oidxA : oidxB;

        if (l == 0)
            k_alar<<<n / 4, 256, 0, stream>>>(cur, att_l, att_r, al, ar, n);

        int nblk = n / 2048;
        k_scan1<<<nblk, 256, 0, stream>>>(degI, rowptr, bsum);
        k_scan2<<<1, 64, 0, stream>>>(bsum, nblk);
        k_scan3s<<<n / 256, 256, 0, stream>>>(rowptr, cursor, bsum, degI, al, ar,
                                              dinv, selfco, keep, nmap, n);

        k_fill<<<(NEDGE + 255) / 256, 256, 0, stream>>>(srcA, dstA, emask, dinv, al, ar,
                                                        cursor, edges);
        k_msg_csr<<<n / 8, 256, 0, stream>>>(rowptr, degI, edges, cur, x, oidx,
                                             selfco, bufH, npg);
        k_pool<<<dim3(G, npg / 256), 128, 0, stream>>>(bufH, pooled, npg, l);

        if (l < 2) {
            int nb = npg / 256;
            k_hist<<<G * nb, 256, 0, stream>>>(score, npg, nb, blockhist);
            k_binprefix<<<G * 8, 256, 0, stream>>>(blockhist, histT, nb);
            k_basepos<<<G, 256, 0, stream>>>(histT, baseposT);
            k_rank<<<G * nb, 256, 0, stream>>>(score, blockhist, baseposT, npg, nb, k,
                                               keep, nmap, perm);
            int m = G * k;
            k_gather_alar<<<(m * 32 + 255) / 256, 256, 0, stream>>>(
                bufH, perm, oidx, att_l + (l + 1) * C, att_r + (l + 1) * C,
                bufC, oidxN, al, ar, degI, score, m);
            k_remap_deg<<<(NEDGE + 255) / 256, 256, 0, stream>>>(srcA, dstA, emask,
                                                                 keep, nmap, degI, score);
        }
    }

    k_tail<<<G, 256, 0, stream>>>(pooled, w_ih, b_ih, b_hh, w_fin, b_fin,
                                  w_root, b_root, rootv, alphap, out);
}